// Round 4
// baseline (446.681 us; speedup 1.0000x reference)
//
#include <hip/hip_runtime.h>
#include <math.h>

#define BATCH    131072
#define IN_DIMS  512
#define TPB      64                 // ONE wave per block: barrier-free design
#define ROWS     64                 // one row per lane
#define NBLK     (BATCH / ROWS)     // 2048 blocks = 8 waves/CU
#define CHUNK    32
#define NCHUNK   (IN_DIMS / CHUNK)  // 16
#define LSTRIDE  33                 // read bank = (l + k) % 32 -> 2 lanes/bank = free

// Wave-autonomous: each 64-lane wave owns 64 rows and a private LDS tile.
// DS ops within a wave execute in program order, so staging chunk c+1 after the
// reads of chunk c needs NO __syncthreads -- the only waits are the compiler's
// fine-grained vmcnt/lgkmcnt, and the vmcnt(0) for the staging write sits after
// 288 FMAs of compute (latency hidden inside the wave's own pipeline).
// W rows are accessed at wave-uniform addresses -> s_load (K$-resident).
__global__ __launch_bounds__(TPB, 2)
void svdo_rot_kernel(const float* __restrict__ x,
                     const float* __restrict__ W,
                     const float* __restrict__ bias,
                     float* __restrict__ out)
{
    __shared__ float tile[ROWS * LSTRIDE];   // 8448 B, private to this wave

    const int l = threadIdx.x;               // lane 0..63
    const int row0 = blockIdx.x * ROWS;
    const float* xb = x + (size_t)row0 * IN_DIMS;

    float acc[9];
#pragma unroll
    for (int j = 0; j < 9; ++j) acc[j] = 0.0f;

    float4 pre[8];

    // lane l, slot i covers row r = i*8 + l/8, cols q*4..q*4+3 (q = l&7):
    // global: 8 lanes x 16 B = 128 B contiguous per row segment (coalesced)
#define LOADCH(c)                                                              \
    do { _Pragma("unroll")                                                     \
        for (int i = 0; i < 8; ++i) {                                          \
            int r = i * 8 + (l >> 3), q = l & 7;                               \
            pre[i] = *reinterpret_cast<const float4*>(                         \
                xb + r * IN_DIMS + (c) * CHUNK + q * 4);                       \
        } } while (0)

#define WRITECH()                                                              \
    do { _Pragma("unroll")                                                     \
        for (int i = 0; i < 8; ++i) {                                          \
            int r = i * 8 + (l >> 3), q = l & 7;                               \
            float* p = &tile[r * LSTRIDE + q * 4];                             \
            p[0] = pre[i].x; p[1] = pre[i].y; p[2] = pre[i].z; p[3] = pre[i].w;\
        } } while (0)

    // prologue: stage chunk 0
    LOADCH(0);
    WRITECH();

#pragma unroll 1
    for (int c = 0; c < NCHUNK; ++c) {
        // read this lane's 32 cols of chunk c (in-order DS: sees prior write)
        float xv[CHUNK];
#pragma unroll
        for (int k = 0; k < CHUNK; ++k) xv[k] = tile[l * LSTRIDE + k];

        // issue next chunk's global loads early (8 dwordx4 in flight)
        if (c + 1 < NCHUNK) LOADCH(c + 1);

        const float* wc = W + c * CHUNK;     // uniform -> s_load
#pragma unroll
        for (int j = 0; j < 9; ++j) {
            float s = acc[j];
            const float* wr = wc + j * IN_DIMS;
#pragma unroll
            for (int k = 0; k < CHUNK; ++k) s = fmaf(xv[k], wr[k], s);
            acc[j] = s;
        }

        // stage chunk c+1 (vmcnt(0) lands here, after the 288 FMAs)
        if (c + 1 < NCHUNK) WRITECH();
    }

    // ---- nearest rotation of the 3x3 M (row-major m[3r+c]), fp32 Jacobi ----
    float m0 = acc[0] + bias[0], m1 = acc[1] + bias[1], m2 = acc[2] + bias[2];
    float m3 = acc[3] + bias[3], m4 = acc[4] + bias[4], m5 = acc[5] + bias[5];
    float m6 = acc[6] + bias[6], m7 = acc[7] + bias[7], m8 = acc[8] + bias[8];

    float A00 = m0*m0 + m3*m3 + m6*m6;
    float A01 = m0*m1 + m3*m4 + m6*m7;
    float A02 = m0*m2 + m3*m5 + m6*m8;
    float A11 = m1*m1 + m4*m4 + m7*m7;
    float A12 = m1*m2 + m4*m5 + m7*m8;
    float A22 = m2*m2 + m5*m5 + m8*m8;

    float V0x = 1.f, V0y = 0.f, V0z = 0.f;
    float V1x = 0.f, V1y = 1.f, V1z = 0.f;
    float V2x = 0.f, V2y = 0.f, V2z = 1.f;

#define JACOBI_ROT(App, Aqq, Apq, Arp, Arq, Px, Py, Pz, Qx, Qy, Qz)            \
    do {                                                                       \
        float dpr = Aqq - App;                                                 \
        float sq  = sqrtf(fmaf(dpr, dpr, 4.0f * Apq * Apq));                   \
        float dd  = dpr + copysignf(sq, dpr);                                  \
        float tt  = (2.0f * Apq) / (dd + copysignf(1e-30f, dd));               \
        float cc  = 1.0f / sqrtf(fmaf(tt, tt, 1.0f));                          \
        float ss  = tt * cc;                                                   \
        App -= tt * Apq; Aqq += tt * Apq;                                      \
        float nrp = cc*Arp - ss*Arq;  Arq = ss*Arp + cc*Arq;  Arp = nrp;       \
        Apq = 0.0f;                                                            \
        float tx = cc*Px - ss*Qx;  Qx = ss*Px + cc*Qx;  Px = tx;               \
        float ty = cc*Py - ss*Qy;  Qy = ss*Py + cc*Qy;  Py = ty;               \
        float tz = cc*Pz - ss*Qz;  Qz = ss*Pz + cc*Qz;  Pz = tz;               \
    } while (0)

#pragma unroll 1
    for (int sweep = 0; sweep < 5; ++sweep) {
        JACOBI_ROT(A00, A11, A01, A02, A12, V0x,V0y,V0z, V1x,V1y,V1z);
        JACOBI_ROT(A00, A22, A02, A01, A12, V0x,V0y,V0z, V2x,V2y,V2z);
        JACOBI_ROT(A11, A22, A12, A01, A02, V1x,V1y,V1z, V2x,V2y,V2z);
    }

#define CSWAP(La, Lb, Ax, Ay, Az, Bx, By, Bz)                                  \
    do { if (La < Lb) { float _t_;                                             \
        _t_ = La; La = Lb; Lb = _t_;                                           \
        _t_ = Ax; Ax = Bx; Bx = _t_;                                           \
        _t_ = Ay; Ay = By; By = _t_;                                           \
        _t_ = Az; Az = Bz; Bz = _t_;                                           \
    } } while (0)

    CSWAP(A00, A11, V0x,V0y,V0z, V1x,V1y,V1z);
    CSWAP(A00, A22, V0x,V0y,V0z, V2x,V2y,V2z);
    CSWAP(A11, A22, V1x,V1y,V1z, V2x,V2y,V2z);

    // u1 = normalize(M v1)
    float b1x = m0*V0x + m1*V0y + m2*V0z;
    float b1y = m3*V0x + m4*V0y + m5*V0z;
    float b1z = m6*V0x + m7*V0y + m8*V0z;
    float inv1 = 1.0f / sqrtf(b1x*b1x + b1y*b1y + b1z*b1z + 1e-30f);
    float u1x = b1x*inv1, u1y = b1y*inv1, u1z = b1z*inv1;

    // u2 = normalize(M v2 - (u1 . M v2) u1)
    float b2x = m0*V1x + m1*V1y + m2*V1z;
    float b2y = m3*V1x + m4*V1y + m5*V1z;
    float b2z = m6*V1x + m7*V1y + m8*V1z;
    float d12 = u1x*b2x + u1y*b2y + u1z*b2z;
    b2x -= d12*u1x; b2y -= d12*u1y; b2z -= d12*u1z;
    float inv2 = 1.0f / sqrtf(b2x*b2x + b2y*b2y + b2z*b2z + 1e-30f);
    float u2x = b2x*inv2, u2y = b2y*inv2, u2z = b2z*inv2;

    // u3 = u1 x u2  (det(U) = +1 by construction)
    float u3x = u1y*u2z - u1z*u2y;
    float u3y = u1z*u2x - u1x*u2z;
    float u3z = u1x*u2y - u1y*u2x;

    // e = sign(det V); R = u1 v1^T + u2 v2^T + e u3 v3^T
    float cxx = V1y*V2z - V1z*V2y;
    float cyy = V1z*V2x - V1x*V2z;
    float czz = V1x*V2y - V1y*V2x;
    float detV = V0x*cxx + V0y*cyy + V0z*czz;
    float e = (detV >= 0.0f) ? 1.0f : -1.0f;
    float w3x = e*u3x, w3y = e*u3y, w3z = e*u3z;

    float* o = out + (size_t)(row0 + l) * 9;
    o[0] = u1x*V0x + u2x*V1x + w3x*V2x;
    o[1] = u1x*V0y + u2x*V1y + w3x*V2y;
    o[2] = u1x*V0z + u2x*V1z + w3x*V2z;
    o[3] = u1y*V0x + u2y*V1x + w3y*V2x;
    o[4] = u1y*V0y + u2y*V1y + w3y*V2y;
    o[5] = u1y*V0z + u2y*V1z + w3y*V2z;
    o[6] = u1z*V0x + u2z*V1x + w3z*V2x;
    o[7] = u1z*V0y + u2z*V1y + w3z*V2y;
    o[8] = u1z*V0z + u2z*V1z + w3z*V2z;
}

extern "C" void kernel_launch(void* const* d_in, const int* in_sizes, int n_in,
                              void* d_out, int out_size, void* d_ws, size_t ws_size,
                              hipStream_t stream) {
    const float* x  = (const float*)d_in[0];
    const float* W  = (const float*)d_in[1];
    const float* b  = (const float*)d_in[2];
    float* out = (float*)d_out;
    svdo_rot_kernel<<<dim3(NBLK), dim3(TPB), 0, stream>>>(x, W, b, out);
}

// Round 5
// 408.665 us; speedup vs baseline: 1.0930x; 1.0930x over previous
//
#include <hip/hip_runtime.h>
#include <math.h>

#define BATCH    131072
#define IN_DIMS  512
#define TPB      256
#define RPB      32                  // rows per block: 8 threads cooperate per row
#define NBLK     (BATCH / RPB)       // 4096 blocks

// No LDS, no barriers. Lane phase q=t&7 covers cols q*4+32*i (8 lanes = 128 B
// contiguous, perfectly coalesced; each row read exactly once). W float4 loads
// dedup to 8 addresses/wave-instr (L1-resident, 18 KB). Cross-lane reduce via
// 3 shfl_xor stages; all 8 lanes of a group redundantly run the Jacobi (same
// wall time as one lane), lane q==0 stores the 9 outputs.
__global__ __launch_bounds__(TPB, 4)
void svdo_rot_kernel(const float* __restrict__ x,
                     const float* __restrict__ W,
                     const float* __restrict__ bias,
                     float* __restrict__ out)
{
    const int t = threadIdx.x;
    const int q = t & 7;                 // phase within row
    const int r = t >> 3;                // local row 0..31
    const int row = blockIdx.x * RPB + r;

    const float* xr  = x + (size_t)row * IN_DIMS + q * 4;
    const float* wq  = W + q * 4;

    float acc[9];
#pragma unroll
    for (int j = 0; j < 9; ++j) acc[j] = 0.0f;

    // ---- phase 1: streaming GEMV, 16 col-steps of 32 floats ----
    float4 xnxt = *reinterpret_cast<const float4*>(xr);
#pragma unroll 2
    for (int i = 0; i < 16; ++i) {
        float4 xc = xnxt;
        if (i + 1 < 16)
            xnxt = *reinterpret_cast<const float4*>(xr + (i + 1) * 32);
        const float* wi = wq + i * 32;
#pragma unroll
        for (int j = 0; j < 9; ++j) {
            float4 wv = *reinterpret_cast<const float4*>(wi + j * IN_DIMS);
            acc[j] = fmaf(xc.x, wv.x, acc[j]);
            acc[j] = fmaf(xc.y, wv.y, acc[j]);
            acc[j] = fmaf(xc.z, wv.z, acc[j]);
            acc[j] = fmaf(xc.w, wv.w, acc[j]);
        }
    }

    // ---- cross-lane reduce within each 8-lane row group ----
    float m[9];
#pragma unroll
    for (int j = 0; j < 9; ++j) {
        float v = acc[j];
        v += __shfl_xor(v, 1);
        v += __shfl_xor(v, 2);
        v += __shfl_xor(v, 4);
        m[j] = v + bias[j];              // all 8 lanes now hold the full sum
    }

    // ---- nearest rotation of the 3x3 M (row-major m[3r+c]), fp32 Jacobi ----
    float m0 = m[0], m1 = m[1], m2 = m[2];
    float m3 = m[3], m4 = m[4], m5 = m[5];
    float m6 = m[6], m7 = m[7], m8 = m[8];

    float A00 = m0*m0 + m3*m3 + m6*m6;
    float A01 = m0*m1 + m3*m4 + m6*m7;
    float A02 = m0*m2 + m3*m5 + m6*m8;
    float A11 = m1*m1 + m4*m4 + m7*m7;
    float A12 = m1*m2 + m4*m5 + m7*m8;
    float A22 = m2*m2 + m5*m5 + m8*m8;

    float V0x = 1.f, V0y = 0.f, V0z = 0.f;
    float V1x = 0.f, V1y = 1.f, V1z = 0.f;
    float V2x = 0.f, V2y = 0.f, V2z = 1.f;

#define JACOBI_ROT(App, Aqq, Apq, Arp, Arq, Px, Py, Pz, Qx, Qy, Qz)            \
    do {                                                                       \
        float dpr = Aqq - App;                                                 \
        float sq  = sqrtf(fmaf(dpr, dpr, 4.0f * Apq * Apq));                   \
        float dd  = dpr + copysignf(sq, dpr);                                  \
        float tt  = (2.0f * Apq) / (dd + copysignf(1e-30f, dd));               \
        float cc  = 1.0f / sqrtf(fmaf(tt, tt, 1.0f));                          \
        float ss  = tt * cc;                                                   \
        App -= tt * Apq; Aqq += tt * Apq;                                      \
        float nrp = cc*Arp - ss*Arq;  Arq = ss*Arp + cc*Arq;  Arp = nrp;       \
        Apq = 0.0f;                                                            \
        float tx = cc*Px - ss*Qx;  Qx = ss*Px + cc*Qx;  Px = tx;               \
        float ty = cc*Py - ss*Qy;  Qy = ss*Py + cc*Qy;  Py = ty;               \
        float tz = cc*Pz - ss*Qz;  Qz = ss*Pz + cc*Qz;  Pz = tz;               \
    } while (0)

#pragma unroll 1
    for (int sweep = 0; sweep < 5; ++sweep) {
        JACOBI_ROT(A00, A11, A01, A02, A12, V0x,V0y,V0z, V1x,V1y,V1z);
        JACOBI_ROT(A00, A22, A02, A01, A12, V0x,V0y,V0z, V2x,V2y,V2z);
        JACOBI_ROT(A11, A22, A12, A01, A02, V1x,V1y,V1z, V2x,V2y,V2z);
    }

#define CSWAP(La, Lb, Ax, Ay, Az, Bx, By, Bz)                                  \
    do { if (La < Lb) { float _t_;                                             \
        _t_ = La; La = Lb; Lb = _t_;                                           \
        _t_ = Ax; Ax = Bx; Bx = _t_;                                           \
        _t_ = Ay; Ay = By; By = _t_;                                           \
        _t_ = Az; Az = Bz; Bz = _t_;                                           \
    } } while (0)

    CSWAP(A00, A11, V0x,V0y,V0z, V1x,V1y,V1z);
    CSWAP(A00, A22, V0x,V0y,V0z, V2x,V2y,V2z);
    CSWAP(A11, A22, V1x,V1y,V1z, V2x,V2y,V2z);

    // u1 = normalize(M v1)
    float b1x = m0*V0x + m1*V0y + m2*V0z;
    float b1y = m3*V0x + m4*V0y + m5*V0z;
    float b1z = m6*V0x + m7*V0y + m8*V0z;
    float inv1 = 1.0f / sqrtf(b1x*b1x + b1y*b1y + b1z*b1z + 1e-30f);
    float u1x = b1x*inv1, u1y = b1y*inv1, u1z = b1z*inv1;

    // u2 = normalize(M v2 - (u1 . M v2) u1)
    float b2x = m0*V1x + m1*V1y + m2*V1z;
    float b2y = m3*V1x + m4*V1y + m5*V1z;
    float b2z = m6*V1x + m7*V1y + m8*V1z;
    float d12 = u1x*b2x + u1y*b2y + u1z*b2z;
    b2x -= d12*u1x; b2y -= d12*u1y; b2z -= d12*u1z;
    float inv2 = 1.0f / sqrtf(b2x*b2x + b2y*b2y + b2z*b2z + 1e-30f);
    float u2x = b2x*inv2, u2y = b2y*inv2, u2z = b2z*inv2;

    // u3 = u1 x u2  (det(U) = +1 by construction)
    float u3x = u1y*u2z - u1z*u2y;
    float u3y = u1z*u2x - u1x*u2z;
    float u3z = u1x*u2y - u1y*u2x;

    // e = sign(det V); R = u1 v1^T + u2 v2^T + e u3 v3^T
    float cxx = V1y*V2z - V1z*V2y;
    float cyy = V1z*V2x - V1x*V2z;
    float czz = V1x*V2y - V1y*V2x;
    float detV = V0x*cxx + V0y*cyy + V0z*czz;
    float e = (detV >= 0.0f) ? 1.0f : -1.0f;
    float w3x = e*u3x, w3y = e*u3y, w3z = e*u3z;

    if (q == 0) {
        float* o = out + (size_t)row * 9;
        o[0] = u1x*V0x + u2x*V1x + w3x*V2x;
        o[1] = u1x*V0y + u2x*V1y + w3x*V2y;
        o[2] = u1x*V0z + u2x*V1z + w3x*V2z;
        o[3] = u1y*V0x + u2y*V1x + w3y*V2x;
        o[4] = u1y*V0y + u2y*V1y + w3y*V2y;
        o[5] = u1y*V0z + u2y*V1z + w3y*V2z;
        o[6] = u1z*V0x + u2z*V1x + w3z*V2x;
        o[7] = u1z*V0y + u2z*V1y + w3z*V2y;
        o[8] = u1z*V0z + u2z*V1z + w3z*V2z;
    }
}

extern "C" void kernel_launch(void* const* d_in, const int* in_sizes, int n_in,
                              void* d_out, int out_size, void* d_ws, size_t ws_size,
                              hipStream_t stream) {
    const float* x  = (const float*)d_in[0];
    const float* W  = (const float*)d_in[1];
    const float* b  = (const float*)d_in[2];
    float* out = (float*)d_out;
    svdo_rot_kernel<<<dim3(NBLK), dim3(TPB), 0, stream>>>(x, W, b, out);
}